// Round 12
// baseline (219.036 us; speedup 1.0000x reference)
//
#include <hip/hip_runtime.h>

// ReadInAttention — 8-launch pipeline, 8-row tiles (2 rows x float4 per
// thread) for 2x TLP vs 16-row version. Weight conversion f32->bf16 for
// Wq/Wv/We/WkT folded into s1 as extra blocks. Dual 8-deep B prefetch,
// b128 LDS A-reads, f32 accumulation.

#define DD 768
#define CDIM 384
#define NH 8
#define HD 64
#define INNER 512
#define VV 256

typedef unsigned short u16;

__device__ __forceinline__ void fma4(float4& a, float s, const float4& b) {
  a.x += s * b.x; a.y += s * b.y; a.z += s * b.z; a.w += s * b.w;
}

__device__ __forceinline__ float4 bexp(uint2 u) {
  float4 r;
  r.x = __uint_as_float(u.x << 16);
  r.y = __uint_as_float(u.x & 0xffff0000u);
  r.z = __uint_as_float(u.y << 16);
  r.w = __uint_as_float(u.y & 0xffff0000u);
  return r;
}

__device__ __forceinline__ u16 f2b(float v) {
  return (u16)((__float_as_uint(v) + 0x8000u) >> 16);
}

// 2-row f32-B core
template <int K, int NS>
__device__ __forceinline__ void gcore2(const float* __restrict__ A0, int lda,
                                       const float* __restrict__ Bp,
                                       float4& a0, float4& a1) {
  float4 b0[8], b1[8];
#pragma unroll
  for (int i = 0; i < 8; i++) b0[i] = *(const float4*)(Bp + (size_t)i * NS);
  const float* Bq = Bp + (size_t)8 * NS;
#pragma unroll 1
  for (int kk = 0; kk < K; kk += 16) {
#pragma unroll
    for (int i = 0; i < 8; i++) b1[i] = *(const float4*)(Bq + (size_t)i * NS);
    Bq += (size_t)8 * NS;
#pragma unroll
    for (int c = 0; c < 2; c++) {
      int kb = kk + c * 4;
      float4 f0 = *(const float4*)(A0 + kb);
      float4 f1 = *(const float4*)(A0 + lda + kb);
      float4 bv;
      bv = b0[c*4+0]; fma4(a0, f0.x, bv); fma4(a1, f1.x, bv);
      bv = b0[c*4+1]; fma4(a0, f0.y, bv); fma4(a1, f1.y, bv);
      bv = b0[c*4+2]; fma4(a0, f0.z, bv); fma4(a1, f1.z, bv);
      bv = b0[c*4+3]; fma4(a0, f0.w, bv); fma4(a1, f1.w, bv);
    }
    if (kk + 16 < K) {
#pragma unroll
      for (int i = 0; i < 8; i++) b0[i] = *(const float4*)(Bq + (size_t)i * NS);
      Bq += (size_t)8 * NS;
    }
#pragma unroll
    for (int c = 0; c < 2; c++) {
      int kb = kk + 8 + c * 4;
      float4 f0 = *(const float4*)(A0 + kb);
      float4 f1 = *(const float4*)(A0 + lda + kb);
      float4 bv;
      bv = b1[c*4+0]; fma4(a0, f0.x, bv); fma4(a1, f1.x, bv);
      bv = b1[c*4+1]; fma4(a0, f0.y, bv); fma4(a1, f1.y, bv);
      bv = b1[c*4+2]; fma4(a0, f0.z, bv); fma4(a1, f1.z, bv);
      bv = b1[c*4+3]; fma4(a0, f0.w, bv); fma4(a1, f1.w, bv);
    }
  }
}

// 2-row bf16-B core
template <int K, int NS>
__device__ __forceinline__ void gcore2b(const float* __restrict__ A0, int lda,
                                        const u16* __restrict__ Bp,
                                        float4& a0, float4& a1) {
  uint2 b0[8], b1[8];
#pragma unroll
  for (int i = 0; i < 8; i++) b0[i] = *(const uint2*)(Bp + (size_t)i * NS);
  const u16* Bq = Bp + (size_t)8 * NS;
#pragma unroll 1
  for (int kk = 0; kk < K; kk += 16) {
#pragma unroll
    for (int i = 0; i < 8; i++) b1[i] = *(const uint2*)(Bq + (size_t)i * NS);
    Bq += (size_t)8 * NS;
#pragma unroll
    for (int c = 0; c < 2; c++) {
      int kb = kk + c * 4;
      float4 f0 = *(const float4*)(A0 + kb);
      float4 f1 = *(const float4*)(A0 + lda + kb);
      float4 bv;
      bv = bexp(b0[c*4+0]); fma4(a0, f0.x, bv); fma4(a1, f1.x, bv);
      bv = bexp(b0[c*4+1]); fma4(a0, f0.y, bv); fma4(a1, f1.y, bv);
      bv = bexp(b0[c*4+2]); fma4(a0, f0.z, bv); fma4(a1, f1.z, bv);
      bv = bexp(b0[c*4+3]); fma4(a0, f0.w, bv); fma4(a1, f1.w, bv);
    }
    if (kk + 16 < K) {
#pragma unroll
      for (int i = 0; i < 8; i++) b0[i] = *(const uint2*)(Bq + (size_t)i * NS);
      Bq += (size_t)8 * NS;
    }
#pragma unroll
    for (int c = 0; c < 2; c++) {
      int kb = kk + 8 + c * 4;
      float4 f0 = *(const float4*)(A0 + kb);
      float4 f1 = *(const float4*)(A0 + lda + kb);
      float4 bv;
      bv = bexp(b1[c*4+0]); fma4(a0, f0.x, bv); fma4(a1, f1.x, bv);
      bv = bexp(b1[c*4+1]); fma4(a0, f0.y, bv); fma4(a1, f1.y, bv);
      bv = bexp(b1[c*4+2]); fma4(a0, f0.z, bv); fma4(a1, f1.z, bv);
      bv = bexp(b1[c*4+3]); fma4(a0, f0.w, bv); fma4(a1, f1.w, bv);
    }
  }
}

// bw ushort layout: bWq 0 | bWv 393216 | bWe 786432 | bWkT 1179648 | end 1572864

// ===== Stage 1: code GEMM [0,352) | WkT conv [352,448) | W conv [448,896) |
//                LN [896,2176) =============================================
__global__ __launch_bounds__(256, 2) void k_s1(
    const float* __restrict__ ss, const float* __restrict__ rs,
    const float* __restrict__ g_s, const float* __restrict__ b_s,
    const float* __restrict__ g_r, const float* __restrict__ b_r,
    const float* __restrict__ codes, const float* __restrict__ Wmq,
    const float* __restrict__ Wmk, const float* __restrict__ Wmv,
    const float* __restrict__ Wme, const float* __restrict__ Wk,
    const float* __restrict__ Wq, const float* __restrict__ Wv,
    const float* __restrict__ We,
    float* __restrict__ s_ln, float* __restrict__ r_ln,
    float* __restrict__ cp, u16* __restrict__ bw) {
  __shared__ __align__(16) float SB[4160];
  int bid = blockIdx.x, t = threadIdx.x;
  if (bid < 352) {  // ---- code GEMM: 8 rows x 256 cols, K=384, f32 B ----
    int nc = bid % 11, mb = bid / 11;
    int base = nc * 256;
    const float* W; int N, colW;
    if (base < 768)       { W = Wmq; N = DD;    colW = base; }
    else if (base < 1536) { W = Wmk; N = DD;    colW = base - 768; }
    else if (base < 2304) { W = Wmv; N = DD;    colW = base - 1536; }
    else                  { W = Wme; N = INNER; colW = base - 2304; }
    int m0 = mb * 8;
#pragma unroll
    for (int p = 0; p < 12; p++) {
      int idx = p * 256 + t, r = idx / 384, k = idx % 384;
      SB[idx] = codes[(size_t)(m0 + r) * CDIM + k];
    }
    __syncthreads();
    int kl = t & 63, wid = t >> 6;
    const float* A0 = SB + (wid * 2) * 384;
    float4 a0 = {0,0,0,0}, a1 = {0,0,0,0};
    if (N == DD)
      gcore2<384, DD>(A0, 384, W + colW + 4 * kl, a0, a1);
    else
      gcore2<384, INNER>(A0, 384, W + colW + 4 * kl, a0, a1);
    int m = m0 + wid * 2, gcol = base + 4 * kl;
    float4 o0 = {1.f + a0.x, 1.f + a0.y, 1.f + a0.z, 1.f + a0.w};
    float4 o1 = {1.f + a1.x, 1.f + a1.y, 1.f + a1.z, 1.f + a1.w};
    *(float4*)(cp + (size_t)m * 2816 + gcol) = o0;
    *(float4*)(cp + (size_t)(m + 1) * 2816 + gcol) = o1;
  } else if (bid < 448) {  // ---- Wk transpose-convert -> bWkT ----
    int tid = bid - 352;
    int d0 = (tid >> 3) * 64, c0 = (tid & 7) * 64;
    int j = t & 63, i0 = t >> 6;
#pragma unroll
    for (int p = 0; p < 16; p++) {
      int i = p * 4 + i0;
      SB[i * 65 + j] = Wk[(size_t)(d0 + i) * INNER + c0 + j];
    }
    __syncthreads();
    u16* dst = bw + 1179648;
#pragma unroll
    for (int p = 0; p < 16; p++) {
      int i = p * 4 + i0;
      dst[(size_t)(c0 + i) * DD + d0 + j] = f2b(SB[j * 65 + i]);
    }
  } else if (bid < 896) {  // ---- convert Wq/Wv/We -> bf16 ----
    for (int idx = (bid - 448) * 256 + t; idx < 294912; idx += 448 * 256) {
      const float* src; u16* dst; int off;
      if (idx < 98304)       { src = Wq; dst = bw;          off = idx; }
      else if (idx < 196608) { src = Wv; dst = bw + 393216; off = idx - 98304; }
      else                   { src = We; dst = bw + 786432; off = idx - 196608; }
      float4 v = *(const float4*)(src + (size_t)off * 4);
      ushort4 o;
      o.x = f2b(v.x); o.y = f2b(v.y); o.z = f2b(v.z); o.w = f2b(v.w);
      *(ushort4*)(dst + (size_t)off * 4) = o;
    }
  } else {  // ---- LayerNorm ----
    int rr = bid - 896;
    const float *x, *g, *bb; float* y; int r;
    if (rr < 1024) { x = ss; g = g_s; bb = b_s; y = s_ln; r = rr; }
    else           { x = rs; g = g_r; bb = b_r; y = r_ln; r = rr - 1024; }
    const float* xr = x + (size_t)r * DD;
    float v0 = xr[t], v1 = xr[t + 256], v2 = xr[t + 512];
    float s = v0 + v1 + v2, sq = v0 * v0 + v1 * v1 + v2 * v2;
    for (int o = 32; o > 0; o >>= 1) {
      s += __shfl_down(s, o, 64); sq += __shfl_down(sq, o, 64);
    }
    int wid = t >> 6, lane = t & 63;
    if (lane == 0) { SB[wid] = s; SB[wid + 4] = sq; }
    __syncthreads();
    float sum = SB[0] + SB[1] + SB[2] + SB[3];
    float ssq = SB[4] + SB[5] + SB[6] + SB[7];
    float mu = sum * (1.0f / 768.0f);
    float var = ssq * (1.0f / 768.0f) - mu * mu;
    float rstd = rsqrtf(var + 1e-5f);
    float* yr = y + (size_t)r * DD;
    yr[t]       = (v0 - mu) * rstd * g[t]       + bb[t];
    yr[t + 256] = (v1 - mu) * rstd * g[t + 256] + bb[t + 256];
    yr[t + 512] = (v2 - mu) * rstd * g[t + 512] + bb[t + 512];
  }
}

// ===== Stage 2: q partial [0,256) (Kc=192, ks=4) | sT [256,448) ============
__global__ __launch_bounds__(256, 2) void k_s2(
    const float* __restrict__ s_ln, const float* __restrict__ r_ln,
    const float* __restrict__ cp, const u16* __restrict__ bw,
    float* __restrict__ sT, float* __restrict__ qp) {
  __shared__ __align__(16) float SB[4160];
  int bid = blockIdx.x, t = threadIdx.x;
  if (bid < 256) {
    int ks = bid & 3, t2 = bid >> 2, nc = t2 & 1, mb = t2 >> 1;
    int m0 = mb * 8, col0 = nc * 256, k0 = ks * 192;
#pragma unroll
    for (int p = 0; p < 6; p++) {
      int idx = p * 256 + t, r = idx / 192, k = idx % 192;
      int d = k0 + k;
      SB[idx] = r_ln[(size_t)(m0 + r) * DD + d] * cp[(size_t)(m0 + r) * 2816 + d];
    }
    __syncthreads();
    int kl = t & 63, wid = t >> 6;
    int col = col0 + 4 * kl;
    const float* A0 = SB + (wid * 2) * 192;
    float4 a0 = {0,0,0,0}, a1 = {0,0,0,0};
    gcore2b<192, INNER>(A0, 192, bw + (size_t)k0 * INNER + col, a0, a1);
    int m = m0 + wid * 2;
    float* dst = qp + (size_t)ks * (256 * INNER);
    *(float4*)(dst + (size_t)m * INNER + col) = a0;
    *(float4*)(dst + (size_t)(m + 1) * INNER + col) = a1;
  } else {
    int tid = bid - 256;
    int vt = tid & 3, dt = (tid >> 2) % 12, b = tid / 48;
    int v0 = vt * 64, d0 = dt * 64;
    int j = t & 63, i0 = t >> 6;
#pragma unroll
    for (int p = 0; p < 16; p++) {
      int i = p * 4 + i0;
      SB[i * 65 + j] = s_ln[(size_t)(b * VV + v0 + i) * DD + d0 + j];
    }
    __syncthreads();
#pragma unroll
    for (int p = 0; p < 16; p++) {
      int i = p * 4 + i0;
      sT[((size_t)b * DD + d0 + i) * VV + v0 + j] = SB[j * 65 + i];
    }
  }
}

// ===== Stage 3: qmk [0,768) (K=64) | qbk [768,1024) ========================
__global__ __launch_bounds__(256, 2) void k_s3(
    const float* __restrict__ qp, const float* __restrict__ bq,
    const u16* __restrict__ bw, const float* __restrict__ cp,
    const float* __restrict__ bk, float* __restrict__ qm,
    float* __restrict__ qbk) {
  __shared__ __align__(16) float SB[512];
  int bid = blockIdx.x, t = threadIdx.x;
  if (bid < 768) {
    int h = bid & 7, dc = (bid >> 3) % 3, mb = bid / 24;
    int m0 = mb * 8;
#pragma unroll
    for (int p = 0; p < 2; p++) {
      int idx = p * 256 + t, r = idx >> 6, c = idx & 63;
      int i = h * HD + c;
      size_t off = (size_t)(m0 + r) * INNER + i;
      SB[idx] = qp[off] + qp[131072 + off] + qp[262144 + off] +
                qp[393216 + off] + bq[i];
    }
    __syncthreads();
    int kl = t & 63, wid = t >> 6;
    int col = dc * 256 + 4 * kl;
    const float* A0 = SB + (wid * 2) * HD;
    float4 a0 = {0,0,0,0}, a1 = {0,0,0,0};
    gcore2b<64, DD>(A0, HD, bw + 1179648 + (size_t)(h * HD) * DD + col, a0, a1);
#pragma unroll
    for (int j = 0; j < 2; j++) {
      float4 a = (j == 0) ? a0 : a1;
      int m = m0 + wid * 2 + j;
      const float* mkp = cp + (size_t)m * 2816 + 768 + col;
      float4 o = {a.x * mkp[0], a.y * mkp[1], a.z * mkp[2], a.w * mkp[3]};
      *(float4*)(qm + ((size_t)m * NH + h) * DD + col) = o;
    }
  } else {
    int m = bid - 768;
    size_t off = (size_t)m * INNER;
    SB[t & 255] = 0.f;  // placate compiler; real store below
    float va = (qp[off + t] + qp[131072 + off + t] + qp[262144 + off + t] +
                qp[393216 + off + t] + bq[t]) * bk[t];
    int t2 = t + 256;
    float vb = (qp[off + t2] + qp[131072 + off + t2] + qp[262144 + off + t2] +
                qp[393216 + off + t2] + bq[t2]) * bk[t2];
    // reduce 512 values -> 8 head sums via wave shuffles on (va) and (vb):
    // thread t covers cols t and t+256. head of col c = c>>6.
    __shared__ float RED[512];
    RED[t] = va; RED[t2] = vb;
    __syncthreads();
    if (t < 8) {
      float a = 0.f;
      for (int c = 0; c < HD; c++) a += RED[t * HD + c];
      qbk[m * NH + t] = a;
    }
  }
}

// ===== Stage 4: scores partial (1024 blocks, Kc=192, ks=4) =================
__global__ __launch_bounds__(256, 2) void k_s4(
    const float* __restrict__ qm, const float* __restrict__ sT,
    float* __restrict__ scp) {
  __shared__ __align__(16) float SB[1536];
  int bid = blockIdx.x, t = threadIdx.x;
  int ks = bid & 3, b = (bid >> 2) & 3, mb = bid >> 4;
  int gi0 = b * 512 + mb * 8, k0 = ks * 192;
#pragma unroll
  for (int p = 0; p < 6; p++) {
    int idx = p * 256 + t, r = idx / 192, k = idx % 192;
    SB[idx] = qm[(size_t)(gi0 + r) * DD + k0 + k];
  }
  __syncthreads();
  int kl = t & 63, wid = t >> 6;
  int col = 4 * kl;
  const float* A0 = SB + (wid * 2) * 192;
  float4 a0 = {0,0,0,0}, a1 = {0,0,0,0};
  gcore2<192, VV>(A0, 192, sT + ((size_t)b * DD + k0) * VV + col, a0, a1);
  int gi = gi0 + wid * 2;
  float* dst = scp + (size_t)ks * (2048 * VV);
  *(float4*)(dst + (size_t)gi * VV + col) = a0;
  *(float4*)(dst + (size_t)(gi + 1) * VV + col) = a1;
}

// ===== Stage 5: softmax + ws GEMM (768 blocks, one u-row each) =============
__global__ __launch_bounds__(256, 2) void k_s5(
    const float* __restrict__ scp, const float* __restrict__ qbk,
    const float* __restrict__ s_ln, const float* __restrict__ cp,
    float* __restrict__ wsm) {
  __shared__ __align__(16) float SC[2048];
  int bid = blockIdx.x, t = threadIdx.x;
  int dc = bid % 3, u = (bid / 3) % 64, b = bid / 192;
  int m = b * 64 + u, gi0 = b * 512 + u * 8;
#pragma unroll
  for (int p = 0; p < 8; p++) {
    int idx = p * 256 + t, h = idx >> 8, c = idx & 255;
    size_t o = (size_t)(gi0 + h) * VV + c;
    float v = scp[o] + scp[524288 + o] + scp[1048576 + o] + scp[1572864 + o];
    SC[idx] = (v + qbk[m * NH + h]) * 0.125f;
  }
  __syncthreads();
  int wid = t >> 6, lane = t & 63;
#pragma unroll
  for (int j = 0; j < 2; j++) {
    int h = wid * 2 + j;
    float x0 = SC[h * 256 + lane],       x1 = SC[h * 256 + lane + 64];
    float x2 = SC[h * 256 + lane + 128], x3 = SC[h * 256 + lane + 192];
    float mx = fmaxf(fmaxf(x0, x1), fmaxf(x2, x3));
    for (int o = 1; o < 64; o <<= 1) mx = fmaxf(mx, __shfl_xor(mx, o, 64));
    float e0 = __expf(x0 - mx), e1 = __expf(x1 - mx);
    float e2 = __expf(x2 - mx), e3 = __expf(x3 - mx);
    float sm = e0 + e1 + e2 + e3;
    for (int o = 1; o < 64; o <<= 1) sm += __shfl_xor(sm, o, 64);
    float rinv = 1.0f / sm;
    SC[h * 256 + lane] = e0 * rinv;       SC[h * 256 + lane + 64] = e1 * rinv;
    SC[h * 256 + lane + 128] = e2 * rinv; SC[h * 256 + lane + 192] = e3 * rinv;
  }
  __syncthreads();
  int kl = t & 63;
  int col = dc * 256 + 4 * kl;
  const float* A0 = SC + (wid * 2) * 256;
  float4 a0 = {0,0,0,0}, a1 = {0,0,0,0};
  gcore2<VV, DD>(A0, 256, s_ln + (size_t)(b * VV) * DD + col, a0, a1);
  const float* mvp = cp + (size_t)m * 2816 + 1536 + col;
  float4 mv4 = {mvp[0], mvp[1], mvp[2], mvp[3]};
#pragma unroll
  for (int j = 0; j < 2; j++) {
    float4 a = (j == 0) ? a0 : a1;
    int h = wid * 2 + j;
    float4 o = {a.x * mv4.x, a.y * mv4.y, a.z * mv4.z, a.w * mv4.w};
    *(float4*)(wsm + ((size_t)h * 256 + m) * DD + col) = o;
  }
}

// ===== Stage 6: msg partial (512 blocks, Kc=96, ks=8) ======================
__global__ __launch_bounds__(256, 2) void k_s6(
    const float* __restrict__ wsm, const u16* __restrict__ bw,
    float* __restrict__ mmp) {
  __shared__ __align__(16) float SB[3088];
  int bid = blockIdx.x, t = threadIdx.x;
  int hp = bid & 1, ks = (bid >> 1) & 7, mb = bid >> 4;
  int h0 = hp * 4, m0 = mb * 8, k0 = ks * 96;
#pragma unroll
  for (int p = 0; p < 12; p++) {
    int idx = p * 256 + t;
    int e = idx / 768, rem = idx % 768, r = rem / 96, k = rem % 96;
    SB[e * 772 + r * 96 + k] =
        wsm[((size_t)(h0 + e) * 256 + m0 + r) * DD + k0 + k];
  }
  __syncthreads();
  int kl = t & 63, wid = t >> 6;
  int hs = kl >> 4, c4 = 4 * (kl & 15);
  int colg = h0 * HD + hs * HD + c4;
  const float* A0 = SB + hs * 772 + (wid * 2) * 96;
  float4 a0 = {0,0,0,0}, a1 = {0,0,0,0};
  gcore2b<96, INNER>(A0, 96, bw + 393216 + (size_t)k0 * INNER + colg, a0, a1);
  float* dst = mmp + (size_t)ks * (256 * INNER);
  int m = m0 + wid * 2;
  *(float4*)(dst + (size_t)m * INNER + colg) = a0;
  *(float4*)(dst + (size_t)(m + 1) * INNER + colg) = a1;
}

// ===== Stage 7: out partial (768 blocks, Kc=64, ks=8) ======================
__global__ __launch_bounds__(256, 2) void k_s7(
    const float* __restrict__ mmp, const float* __restrict__ bvv,
    const float* __restrict__ cp, const u16* __restrict__ bw,
    float* __restrict__ op) {
  __shared__ __align__(16) float SB[512];
  int bid = blockIdx.x, t = threadIdx.x;
  int ks = bid & 7, dc = (bid >> 3) % 3, mb = bid / 24;
  int m0 = mb * 8, k0 = ks * 64;
#pragma unroll
  for (int p = 0; p < 2; p++) {
    int idx = p * 256 + t, r = idx >> 6, k = idx & 63;
    int i = k0 + k;
    size_t off = (size_t)(m0 + r) * INNER + i;
    float v = mmp[off] + mmp[131072 + off] + mmp[262144 + off] +
              mmp[393216 + off] + mmp[524288 + off] + mmp[655360 + off] +
              mmp[786432 + off] + mmp[917504 + off];
    SB[idx] = (v + bvv[i]) * cp[(size_t)(m0 + r) * 2816 + 2304 + i];
  }
  __syncthreads();
  int kl = t & 63, wid = t >> 6;
  int col = dc * 256 + 4 * kl;
  const float* A0 = SB + (wid * 2) * 64;
  float4 a0 = {0,0,0,0}, a1 = {0,0,0,0};
  gcore2b<64, DD>(A0, 64, bw + 786432 + (size_t)k0 * DD + col, a0, a1);
  float* dst = op + (size_t)ks * (256 * DD);
  int m = m0 + wid * 2;
  *(float4*)(dst + (size_t)m * DD + col) = a0;
  *(float4*)(dst + (size_t)(m + 1) * DD + col) = a1;
}

// ===== Stage 8: epilogue (256 blocks) ======================================
__global__ __launch_bounds__(256) void k_s8(
    const float* __restrict__ op, const float* __restrict__ be,
    const float* __restrict__ gamma, const float* __restrict__ rs,
    float* __restrict__ outp) {
  int m = blockIdx.x, t = threadIdx.x;
#pragma unroll
  for (int j = 0; j < 3; j++) {
    int d = t + j * 256;
    size_t off = (size_t)m * DD + d;
    float v = op[off] + op[196608 + off] + op[393216 + off] +
              op[589824 + off] + op[786432 + off] + op[983040 + off] +
              op[1179648 + off] + op[1376256 + off];
    outp[off] = rs[off] + (v + be[d]) * gamma[d];
  }
}

extern "C" void kernel_launch(void* const* d_in, const int* in_sizes, int n_in,
                              void* d_out, int out_size, void* d_ws, size_t ws_size,
                              hipStream_t stream) {
  const float* rs     = (const float*)d_in[0];
  const float* codes  = (const float*)d_in[1];
  const float* ss     = (const float*)d_in[2];
  const float* ln_r_g = (const float*)d_in[3];
  const float* ln_r_b = (const float*)d_in[4];
  const float* ln_s_g = (const float*)d_in[5];
  const float* ln_s_b = (const float*)d_in[6];
  const float* Wq  = (const float*)d_in[7];
  const float* bq  = (const float*)d_in[8];
  const float* Wmq = (const float*)d_in[9];
  const float* Wk  = (const float*)d_in[10];
  const float* bk  = (const float*)d_in[11];
  const float* Wmk = (const float*)d_in[12];
  const float* Wv  = (const float*)d_in[13];
  const float* bv  = (const float*)d_in[14];
  const float* Wmv = (const float*)d_in[15];
  const float* We  = (const float*)d_in[16];
  const float* be  = (const float*)d_in[17];
  const float* Wme = (const float*)d_in[18];
  const float* gamma = (const float*)d_in[19];

  float* w = (float*)d_ws;
  // liveness-aliased layout (float offsets); cp holds 1+codes@Wm* directly.
  float* s_ln = w;                  // 786432   (s1 -> s5)
  float* r_ln = w + 786432;         // 196608   (s1 -> s2)
  float* qp   = w + 1376256;        // 524288   (s2 -> s3, 4 partials)
  float* sT   = w + 1900544;        // 786432   (s2 -> s4)
  float* cp   = w + 2686976;        // 720896   (s1 -> s7) [m][2816], value = 1+mod
  float* qbk  = w + 3407872;        // 2048     (s3 -> s5)
  float* qm   = w + 3409920;        // 1572864  (s3 -> s4)
  float* scp  = w + 4982784;        // 2097152  (s4 -> s5, 4 partials)
  float* wsm  = qm;                 // alias (s5 -> s6)
  float* mmp  = r_ln;               // alias r_ln..qp region (s6 -> s7, 8 partials)
  float* op   = scp;                // alias (s7 -> s8, 8 partials)
  u16*   bw   = (u16*)(w + 7079936); // 1572864 ushorts (s1 -> s7)

  k_s1<<<dim3(2176), 256, 0, stream>>>(ss, rs, ln_s_g, ln_s_b, ln_r_g, ln_r_b,
                                       codes, Wmq, Wmk, Wmv, Wme, Wk, Wq, Wv,
                                       We, s_ln, r_ln, cp, bw);
  k_s2<<<dim3(448), 256, 0, stream>>>(s_ln, r_ln, cp, bw, sT, qp);
  k_s3<<<dim3(1024), 256, 0, stream>>>(qp, bq, bw, cp, bk, qm, qbk);
  k_s4<<<dim3(1024), 256, 0, stream>>>(qm, sT, scp);
  k_s5<<<dim3(768), 256, 0, stream>>>(scp, qbk, s_ln, cp, wsm);
  k_s6<<<dim3(512), 256, 0, stream>>>(wsm, bw, mmp);
  k_s7<<<dim3(768), 256, 0, stream>>>(mmp, bv, cp, bw, op);
  k_s8<<<dim3(256), 256, 0, stream>>>(op, be, gamma, rs, (float*)d_out);
}